// Round 22
// baseline (195.235 us; speedup 1.0000x reference)
//
#include <hip/hip_runtime.h>

#define B_ 4
#define S_ 2048
#define D_ 1024
#define H_ 16
#define E_ 64
#define M_ (B_*S_)   // 8192

typedef __attribute__((ext_vector_type(8))) short short8;    // 8 bf16 = 4 VGPRs (MFMA A/B frag)
typedef __attribute__((ext_vector_type(4))) float floatx4;   // 16x16 MFMA C/D frag
typedef __attribute__((ext_vector_type(16))) float floatx16; // 32x32 MFMA C/D frag

// async global->LDS, 16B per lane; dest must be linear (wave base + lane*16)
#define GLD16(g, l) __builtin_amdgcn_global_load_lds( \
    (const __attribute__((address_space(1))) unsigned*)(g), \
    (__attribute__((address_space(3))) unsigned*)(l), 16, 0, 0)

__device__ __forceinline__ ushort f2b(float f) {   // fp32 -> bf16 RNE
    union { float f; unsigned u; } v; v.f = f;
    unsigned r = v.u + 0x7fffu + ((v.u >> 16) & 1u);
    return (ushort)(r >> 16);
}
__device__ __forceinline__ unsigned cvt_pk_bf16(float lo, float hi) {  // 2xf32 -> packed bf16x2
    unsigned r;
    asm("v_cvt_pk_bf16_f32 %0, %1, %2" : "=v"(r) : "v"(lo), "v"(hi));
    return r;
}
__device__ __forceinline__ float fast_exp2(float x) {
#if __has_builtin(__builtin_amdgcn_exp2f)
    return __builtin_amdgcn_exp2f(x);
#else
    float r; asm("v_exp_f32 %0, %1" : "=v"(r) : "v"(x)); return r;
#endif
}
__device__ __forceinline__ float lane_pull(float v, int srclane) {  // pull v from lane srclane
    return __int_as_float(__builtin_amdgcn_ds_bpermute(srclane << 2, __float_as_int(v)));
}

// ---------------- merged prologue: cast x (blocks 0..2047), cast Wp (2048..2559),
// ---------------- transpose_w (2560..3327). Independent parts, one dispatch.
__global__ __launch_bounds__(256) void prologue(const float* __restrict__ x,
                                                const float* __restrict__ Wq,
                                                const float* __restrict__ Wk,
                                                const float* __restrict__ Wv,
                                                const float* __restrict__ Wp,
                                                ushort* __restrict__ xb,
                                                ushort* __restrict__ wpb,
                                                ushort* __restrict__ wt) {
    __shared__ __align__(16) ushort T[64 * 80];   // used by transpose_w part only
    const int bid = blockIdx.x;
    const int t = threadIdx.x;

    if (bid < 2048) {                      // cast x: 8M elements = 1M chunks of 8
        const int n8 = (int)((size_t)M_ * D_ / 8);
        int i = bid * 256 + t;
        const int stride = 2048 * 256;
        for (; i < n8; i += stride) {
            float4 a = ((const float4*)x)[2 * i];
            float4 b = ((const float4*)x)[2 * i + 1];
            short8 o;
            o[0] = (short)f2b(a.x); o[1] = (short)f2b(a.y);
            o[2] = (short)f2b(a.z); o[3] = (short)f2b(a.w);
            o[4] = (short)f2b(b.x); o[5] = (short)f2b(b.y);
            o[6] = (short)f2b(b.z); o[7] = (short)f2b(b.w);
            ((short8*)xb)[i] = o;
        }
    } else if (bid < 2560) {               // cast Wp: 1M elements = 128K chunks (512 blocks exactly)
        int i = (bid - 2048) * 256 + t;
        float4 a = ((const float4*)Wp)[2 * i];
        float4 b = ((const float4*)Wp)[2 * i + 1];
        short8 o;
        o[0] = (short)f2b(a.x); o[1] = (short)f2b(a.y);
        o[2] = (short)f2b(a.z); o[3] = (short)f2b(a.w);
        o[4] = (short)f2b(b.x); o[5] = (short)f2b(b.y);
        o[6] = (short)f2b(b.z); o[7] = (short)f2b(b.w);
        ((short8*)wpb)[i] = o;
    } else {                               // transpose_w: 768 blocks = 16 d-tiles x 48 heads
        const int q = bid - 2560;
        const int g = q >> 4;              // 0..47 (w*16+h)
        const int d0 = (q & 15) * 64;
        const float* W = (g < 16 ? Wq : (g < 32 ? Wk : Wv)) + (size_t)(g & 15) * (D_ * E_);
        #pragma unroll
        for (int it = 0; it < 4; ++it) {   // 64 d-rows x 16 float4 cols
            int i = it * 256 + t;
            int r = i >> 4, c = i & 15;
            float4 xx = *(const float4*)(W + (size_t)(d0 + r) * E_ + c * 4);
            T[(c * 4 + 0) * 80 + r] = f2b(xx.x);
            T[(c * 4 + 1) * 80 + r] = f2b(xx.y);
            T[(c * 4 + 2) * 80 + r] = f2b(xx.z);
            T[(c * 4 + 3) * 80 + r] = f2b(xx.w);
        }
        __syncthreads();
        #pragma unroll
        for (int it = 0; it < 2; ++it) {   // 64 e-rows x 8 chunks of 8
            int i = it * 256 + t;
            int e = i >> 3, c = i & 7;
            short8 xx = *(const short8*)&T[e * 80 + c * 8];
            *(short8*)&wt[((size_t)g * E_ + e) * D_ + d0 + c * 8] = xx;
        }
    }
}

// ---------------- QKV GEMM: [8192 x 1024] @ [1024 x 3072] (concat W), bf16 MFMA -------
// 2-phase double-buffered LDS (round-21, measured). Tile 256x128, 512 threads.
// w==2 (V) blocks write TRANSPOSED [bh][e][s] directly.
__global__ __launch_bounds__(512) void gemm_qkv(const ushort* __restrict__ xb,
                                                const ushort* __restrict__ wt,
                                                ushort* __restrict__ qk,
                                                ushort* __restrict__ vt) {
    const int m0 = blockIdx.x * 256;
    const int n0 = blockIdx.y * 128;
    const int w  = n0 >> 10;             // 0:q 1:k 2:v (block-uniform)

    __shared__ __align__(16) ushort As[2][256 * 32];   // swizzled, double-buffered
    __shared__ __align__(16) ushort Bs[2][128 * 32];

    const int t = threadIdx.x, l = t & 63, wid = t >> 6;
    const int wm = (wid & 3) * 64, wn = (wid >> 2) * 64;
    floatx4 acc[4][4] = {};

    // prologue: stage first K-step into buf 0
    {
        #pragma unroll
        for (int it = 0; it < 2; ++it) {
            int i = it * 512 + t;
            int r = i >> 2, cs = i & 3;
            int c = cs ^ ((r >> 1) & 3);
            GLD16(xb + (size_t)(m0 + r) * D_ + c * 8, &As[0][i * 8]);
        }
        int r = t >> 2, cs = t & 3;
        int c = cs ^ ((r >> 1) & 3);
        GLD16(wt + (size_t)(n0 + r) * D_ + c * 8, &Bs[0][t * 8]);
    }
    __syncthreads();

    int buf = 0;
    for (int k0 = 0; k0 < D_; k0 += 32) {
        if (k0 + 32 < D_) {
            #pragma unroll
            for (int it = 0; it < 2; ++it) {
                int i = it * 512 + t;
                int r = i >> 2, cs = i & 3;
                int c = cs ^ ((r >> 1) & 3);
                GLD16(xb + (size_t)(m0 + r) * D_ + k0 + 32 + c * 8, &As[buf ^ 1][i * 8]);
            }
            int r = t >> 2, cs = t & 3;
            int c = cs ^ ((r >> 1) & 3);
            GLD16(wt + (size_t)(n0 + r) * D_ + k0 + 32 + c * 8, &Bs[buf ^ 1][t * 8]);
        }

        short8 af[4], bf[4];
        #pragma unroll
        for (int mf = 0; mf < 4; ++mf) {
            int row = wm + 16 * mf + (l & 15);
            int c = (l >> 4) ^ ((row >> 1) & 3);
            af[mf] = *(const short8*)&As[buf][row * 32 + c * 8];
        }
        #pragma unroll
        for (int nf = 0; nf < 4; ++nf) {
            int row = wn + 16 * nf + (l & 15);
            int c = (l >> 4) ^ ((row >> 1) & 3);
            bf[nf] = *(const short8*)&Bs[buf][row * 32 + c * 8];
        }
        #pragma unroll
        for (int mf = 0; mf < 4; ++mf)
            #pragma unroll
            for (int nf = 0; nf < 4; ++nf)
                acc[mf][nf] = __builtin_amdgcn_mfma_f32_16x16x32_bf16(af[mf], bf[nf], acc[mf][nf], 0, 0, 0);

        __syncthreads();
        buf ^= 1;
    }

    if (w < 2) {
        ushort* outw = qk + (size_t)w * ((size_t)B_ * H_ * S_ * E_);
        #pragma unroll
        for (int mf = 0; mf < 4; ++mf)
            #pragma unroll
            for (int nf = 0; nf < 4; ++nf) {
                int n = n0 + wn + 16 * nf + (l & 15);
                int h = (n >> 6) & 15, e = n & 63;
                #pragma unroll
                for (int r = 0; r < 4; ++r) {
                    int m = m0 + wm + 16 * mf + (l >> 4) * 4 + r;
                    int b = m >> 11, s = m & (S_ - 1);
                    outw[((size_t)((b << 4) + h) * S_ + s) * E_ + e] = f2b(acc[mf][nf][r]);
                }
            }
    } else {
        #pragma unroll
        for (int mf = 0; mf < 4; ++mf) {
            int m = m0 + wm + 16 * mf + (l >> 4) * 4;
            int b = m >> 11, s = m & (S_ - 1);
            #pragma unroll
            for (int nf = 0; nf < 4; ++nf) {
                int n = n0 + wn + 16 * nf + (l & 15);
                int h = (n >> 6) & 15, e = n & 63;
                unsigned pk0 = cvt_pk_bf16(acc[mf][nf][0], acc[mf][nf][1]);
                unsigned pk1 = cvt_pk_bf16(acc[mf][nf][2], acc[mf][nf][3]);
                *(uint2*)&vt[((size_t)((b << 4) + h) * E_ + e) * S_ + s] = make_uint2(pk0, pk1);
            }
        }
    }
}

// ---------------- Flash attention (causal), 32x32x16 bf16 MFMA, swapped QK^T ----------
// grid: 1024 blocks x 128 threads (2 waves x 32 q-rows). Block n: x = n>>6, bh = n&63
// (XCD = n%8 = bh%8). Balanced pairs {x, 31-x} = 33 KV-tiles per block.
// 32x32 fragments double FLOPs per LDS read: per q-row, DS ops 1.375 -> 0.875.
// Swapped mfma(K,Q): C/D col=lane&31 = q (lane-local row), rows = kv pattern
// (reg&3)+8*(reg>>2)+4*(lane>>5); lanes l and l+32 share q with complementary kv
// halves -> row reduce = 31 in-lane fmax + one xor32 shuffle.
// LDS 40 KB: QP[64x64] (Q staging, then per-wave 32x64 P), Ks[2]/Vs[2] dbuf.
__global__ __launch_bounds__(128) void flash(const ushort* __restrict__ qg,
                                             const ushort* __restrict__ kg,
                                             const ushort* __restrict__ vtg,
                                             ushort* __restrict__ attn) {
    const int n = blockIdx.x;
    const int x = n >> 6;          // 0..15
    const int bh = n & 63;
    const int b = bh >> 4, h = bh & 15;
    const ushort* qb = qg + (size_t)bh * (S_ * E_);
    const ushort* kb = kg + (size_t)bh * (S_ * E_);
    const ushort* vb = vtg + (size_t)bh * (E_ * S_);

    __shared__ __align__(16) ushort QP[64 * 64];      // Q staging [q][e] swizzled, THEN per-wave P
    __shared__ __align__(16) ushort Ks[2][64 * 64];   // [kv][e] swizzled, double-buffered
    __shared__ __align__(16) ushort Vs[2][64 * 64];   // [e][kv] swizzled, double-buffered

    const int t = threadIdx.x, l = t & 63, wid = t >> 6;   // wid 0..1
    const float SC = 0.18033688f;                  // (1/sqrt(E)) * log2(e)
    const float NEG_INF = -__builtin_inff();
    const int half = l >> 5;                       // k-half selector (0/1)
    const int lq = l & 31;                         // lane's q (wave-local)
    const int qts[2] = {x, 31 - x};
    ushort* Pw = &QP[wid * 2048];                  // this wave's 32x64 P half

    #pragma unroll 1
    for (int qi = 0; qi < 2; ++qi) {
        const int qt = qts[qi];

        // prologue: stage Q + first K/V tile (512 chunks each / 128 thr = 4 iters)
        #pragma unroll
        for (int it = 0; it < 4; ++it) {
            int i = it * 128 + t;
            int r = i >> 3, cs = i & 7, c = cs ^ (r & 7);
            GLD16(qb + (size_t)(qt * 64 + r) * E_ + c * 8, &QP[i * 8]);
            GLD16(kb + (size_t)r * E_ + c * 8, &Ks[0][i * 8]);
            GLD16(vb + (size_t)r * S_ + c * 8, &Vs[0][i * 8]);
        }
        __syncthreads();

        // Q B-frags (4 e-chunks of 16), hoisted to registers; QP dead for Q after this
        short8 qf[4];
        #pragma unroll
        for (int ec = 0; ec < 4; ++ec) {
            int row = wid * 32 + lq;
            int cc = ec * 2 + half;
            int c = cc ^ (row & 7);
            qf[ec] = *(const short8*)&QP[row * 64 + c * 8];
        }

        floatx16 o[2] = {};
        float mr = NEG_INF, lr = 0.f;

        int buf = 0;
        for (int jt = 0; jt <= qt; ++jt) {
            // issue next tile's staging BEFORE compute (latency hides under compute)
            if (jt < qt) {
                #pragma unroll
                for (int it = 0; it < 4; ++it) {
                    int i = it * 128 + t;
                    int r = i >> 3, cs = i & 7, c = cs ^ (r & 7);
                    GLD16(kb + (size_t)((jt + 1) * 64 + r) * E_ + c * 8, &Ks[buf ^ 1][i * 8]);
                    GLD16(vb + (size_t)r * S_ + (jt + 1) * 64 + c * 8, &Vs[buf ^ 1][i * 8]);
                }
            }

            // S = Q K^T swapped: s[mt] lane holds q=lq, kv = mt*32+(reg&3)+8(reg>>2)+4*half
            floatx16 s[2] = {};
            #pragma unroll
            for (int ec = 0; ec < 4; ++ec) {
                int cc = ec * 2 + half;
                {
                    int row = lq;
                    int c = cc ^ (row & 7);
                    short8 kf = *(const short8*)&Ks[buf][row * 64 + c * 8];
                    s[0] = __builtin_amdgcn_mfma_f32_32x32x16_bf16(kf, qf[ec], s[0], 0, 0, 0);
                }
                {
                    int row = 32 + lq;
                    int c = cc ^ (row & 7);
                    short8 kf = *(const short8*)&Ks[buf][row * 64 + c * 8];
                    s[1] = __builtin_amdgcn_mfma_f32_32x32x16_bf16(kf, qf[ec], s[1], 0, 0, 0);
                }
            }

            // causal mask on diagonal tile only
            if (jt == qt) {
                int qg_ = wid * 32 + lq;
                #pragma unroll
                for (int mt = 0; mt < 2; ++mt)
                    #pragma unroll
                    for (int reg = 0; reg < 16; ++reg) {
                        int kvloc = mt * 32 + (reg & 3) + 8 * (reg >> 2) + 4 * half;
                        if (kvloc > qg_) s[mt][reg] = NEG_INF;
                    }
            }

            // row max: 31 in-lane fmax + one xor32 (partner lane holds other kv half)
            float mx = s[0][0];
            #pragma unroll
            for (int mt = 0; mt < 2; ++mt)
                #pragma unroll
                for (int reg = 0; reg < 16; ++reg) mx = fmaxf(mx, s[mt][reg]);
            mx = fmaxf(mx, __shfl_xor(mx, 32));
            bool ok = (mx - mr) * SC <= 8.0f;

            if (!__all(ok)) {   // rescale path (rare after warm-up)
                float mn = fmaxf(mr, mx);
                float al = fast_exp2((mr - mn) * SC);
                mr = mn;
                lr *= al;
                #pragma unroll
                for (int reg = 0; reg < 16; ++reg) {   // o rows: q = (reg&3)+8(reg>>2)+4*half
                    float alq = lane_pull(al, (reg & 3) + 8 * (reg >> 2) + 4 * half);
                    o[0][reg] *= alq;
                    o[1][reg] *= alq;
                }
            }

            // exp2(fma) + lane-partial row sum
            {
                float nm = -mr * SC;
                float rs = 0.f;
                #pragma unroll
                for (int mt = 0; mt < 2; ++mt)
                    #pragma unroll
                    for (int reg = 0; reg < 16; ++reg) {
                        float p = fast_exp2(fmaf(s[mt][reg], SC, nm));
                        s[mt][reg] = p;
                        rs += p;
                    }
                lr += rs;
            }

            // P write: per (mt, r4) 4 consecutive kv -> one b64; row = lq
            #pragma unroll
            for (int mt = 0; mt < 2; ++mt)
                #pragma unroll
                for (int r4 = 0; r4 < 4; ++r4) {
                    unsigned pk0 = cvt_pk_bf16(s[mt][4 * r4 + 0], s[mt][4 * r4 + 1]);
                    unsigned pk1 = cvt_pk_bf16(s[mt][4 * r4 + 2], s[mt][4 * r4 + 3]);
                    int cc = mt * 4 + r4;
                    int sc = cc ^ (lq & 7);
                    *(uint2*)&Pw[lq * 64 + sc * 8 + 4 * half] = make_uint2(pk0, pk1);
                }

            // O += P V: A = P[q32][kv], B = V[e32][kv]
            short8 pf[4];
            #pragma unroll
            for (int kc = 0; kc < 4; ++kc) {
                int cc = kc * 2 + half;
                int c = cc ^ (lq & 7);
                pf[kc] = *(const short8*)&Pw[lq * 64 + c * 8];
            }
            #pragma unroll
            for (int nt = 0; nt < 2; ++nt)
                #pragma unroll
                for (int kc = 0; kc < 4; ++kc) {
                    int row = nt * 32 + lq;
                    int cc = kc * 2 + half;
                    int c = cc ^ (row & 7);
                    short8 vf = *(const short8*)&Vs[buf][row * 64 + c * 8];
                    o[nt] = __builtin_amdgcn_mfma_f32_32x32x16_bf16(pf[kc], vf, o[nt], 0, 0, 0);
                }

            __syncthreads();   // drains this iteration's prefetch (vmcnt) + protects buf^1
            buf ^= 1;
        }

        // epilogue: complete row sum (xor32), distribute 1/l to o-rows, write out
        lr += __shfl_xor(lr, 32);
        float inv = 1.0f / lr;

        #pragma unroll
        for (int reg = 0; reg < 16; ++reg) {
            int qrow = (reg & 3) + 8 * (reg >> 2) + 4 * half;
            float il = lane_pull(inv, qrow);
            #pragma unroll
            for (int nt = 0; nt < 2; ++nt) {
                unsigned pk = cvt_pk_bf16(o[nt][reg] * il, 0.f);
                int e = nt * 32 + lq;
                int cc = e >> 3;
                int sc = cc ^ (qrow & 7);
                Pw[qrow * 64 + sc * 8 + (e & 7)] = (ushort)pk;
            }
        }
        // coalesced store: per wave 32 rows x 8 chunks = 256 chunks / 64 lanes = 4 iters
        #pragma unroll
        for (int it = 0; it < 4; ++it) {
            int i = it * 64 + l;
            int row = i >> 3, ccx = i & 7;
            int c = ccx ^ (row & 7);
            short8 vv = *(const short8*)&Pw[row * 64 + c * 8];
            int s_abs = qt * 64 + wid * 32 + row;
            *(short8*)&attn[((size_t)(b * S_ + s_abs)) * D_ + h * E_ + ccx * 8] = vv;
        }
        __syncthreads();   // all waves done with QP before next q-tile's Q staging
    }
}

// ---------------- output projection: [8192x1024] x Wp^T + bp, bf16 MFMA, fp32 out ----
// 2-phase double-buffered LDS (round-21, measured). 32 KB LDS.
__global__ __launch_bounds__(256) void out_proj(const ushort* __restrict__ a,
                                                const ushort* __restrict__ wpb,
                                                const float* __restrict__ bp,
                                                float* __restrict__ out) {
    const int m0 = blockIdx.x * 128;
    const int n0 = blockIdx.y * 128;

    __shared__ __align__(16) ushort As[2][128 * 32];
    __shared__ __align__(16) ushort Bs[2][128 * 32];

    const int t = threadIdx.x, l = t & 63, wid = t >> 6;
    const int wm = (wid & 1) * 64, wn = (wid >> 1) * 64;
    floatx4 acc[4][4] = {};

    #pragma unroll
    for (int it = 0; it < 2; ++it) {
        int i = it * 256 + t;
        int r = i >> 2, cs = i & 3;
        int c = cs ^ ((r >> 1) & 3);
        GLD16(a + (size_t)(m0 + r) * D_ + c * 8, &As[0][i * 8]);
        GLD16(wpb + (size_t)(n0 + r) * D_ + c * 8, &Bs[0][i * 8]);
    }
    __syncthreads();

    int buf = 0;
    for (int k0 = 0; k0 < D_; k0 += 32) {
        if (k0 + 32 < D_) {
            #pragma unroll
            for (int it = 0; it < 2; ++it) {
                int i = it * 256 + t;
                int r = i >> 2, cs = i & 3;
                int c = cs ^ ((r >> 1) & 3);
                GLD16(a + (size_t)(m0 + r) * D_ + k0 + 32 + c * 8, &As[buf ^ 1][i * 8]);
                GLD16(wpb + (size_t)(n0 + r) * D_ + k0 + 32 + c * 8, &Bs[buf ^ 1][i * 8]);
            }
        }

        short8 af[4], bf[4];
        #pragma unroll
        for (int mf = 0; mf < 4; ++mf) {
            int row = wm + 16 * mf + (l & 15);
            int c = (l >> 4) ^ ((row >> 1) & 3);
            af[mf] = *(const short8*)&As[buf][row * 32 + c * 8];
        }
        #pragma unroll
        for (int nf = 0; nf < 4; ++nf) {
            int row = wn + 16 * nf + (l & 15);
            int c = (l >> 4) ^ ((row >> 1) & 3);
            bf[nf] = *(const short8*)&Bs[buf][row * 32 + c * 8];
        }
        #pragma unroll
        for (int mf = 0; mf < 4; ++mf)
            #pragma unroll
            for (int nf = 0; nf < 4; ++nf)
                acc[mf][nf] = __builtin_amdgcn_mfma_f32_16x16x32_bf16(af[mf], bf[nf], acc[mf][nf], 0, 0, 0);

        __syncthreads();
        buf ^= 1;
    }

    #pragma unroll
    for (int nf = 0; nf < 4; ++nf) {
        int col = n0 + wn + 16 * nf + (l & 15);
        float bias = bp[col];
        #pragma unroll
        for (int mf = 0; mf < 4; ++mf)
            #pragma unroll
            for (int r = 0; r < 4; ++r) {
                int m = m0 + wm + 16 * mf + (l >> 4) * 4 + r;
                out[(size_t)m * D_ + col] = acc[mf][nf][r] + bias;
            }
    }
}

extern "C" void kernel_launch(void* const* d_in, const int* in_sizes, int n_in,
                              void* d_out, int out_size, void* d_ws, size_t ws_size,
                              hipStream_t stream) {
    const float* x  = (const float*)d_in[0];
    const float* Wq = (const float*)d_in[1];
    const float* Wk = (const float*)d_in[2];
    const float* Wv = (const float*)d_in[3];
    const float* Wp = (const float*)d_in[4];
    const float* bp = (const float*)d_in[5];

    ushort* ws = (ushort*)d_ws;
    const size_t NX  = (size_t)M_ * D_;          // 8M
    const size_t NW  = (size_t)48 * E_ * D_;     // 3.15M
    const size_t NP  = (size_t)D_ * D_;          // 1M
    const size_t QSZ = (size_t)B_ * H_ * S_ * E_;// 8M
    ushort* xb    = ws;
    ushort* wt    = xb + NX;
    ushort* wpb   = wt + NW;
    ushort* qk    = wpb + NP;        // q | k
    ushort* vt    = qk + 2 * QSZ;    // v, transposed [bh][e][s]
    ushort* attnb = vt + QSZ;

    prologue <<<3328, 256, 0, stream>>>(x, Wq, Wk, Wv, Wp, xb, wpb, wt);
    gemm_qkv <<<dim3(M_ / 256, 24), 512, 0, stream>>>(xb, wt, qk, vt);
    flash    <<<1024, 128, 0, stream>>>(qk, qk + QSZ, vt, attnb);
    out_proj <<<dim3(M_ / 128, D_ / 128), 256, 0, stream>>>(attnb, wpb, bp, (float*)d_out);
}

// Round 23
// 177.250 us; speedup vs baseline: 1.1015x; 1.1015x over previous
//
#include <hip/hip_runtime.h>

#define B_ 4
#define S_ 2048
#define D_ 1024
#define H_ 16
#define E_ 64
#define M_ (B_*S_)   // 8192

typedef __attribute__((ext_vector_type(8))) short short8;   // 8 bf16 = 4 VGPRs (MFMA A/B frag)
typedef __attribute__((ext_vector_type(4))) float floatx4;  // MFMA C/D frag

// async global->LDS, 16B per lane; dest must be linear (wave base + lane*16)
#define GLD16(g, l) __builtin_amdgcn_global_load_lds( \
    (const __attribute__((address_space(1))) unsigned*)(g), \
    (__attribute__((address_space(3))) unsigned*)(l), 16, 0, 0)

__device__ __forceinline__ ushort f2b(float f) {   // fp32 -> bf16 RNE
    union { float f; unsigned u; } v; v.f = f;
    unsigned r = v.u + 0x7fffu + ((v.u >> 16) & 1u);
    return (ushort)(r >> 16);
}
__device__ __forceinline__ unsigned cvt_pk_bf16(float lo, float hi) {  // 2xf32 -> packed bf16x2
    unsigned r;
    asm("v_cvt_pk_bf16_f32 %0, %1, %2" : "=v"(r) : "v"(lo), "v"(hi));
    return r;
}
__device__ __forceinline__ float fast_exp2(float x) {
#if __has_builtin(__builtin_amdgcn_exp2f)
    return __builtin_amdgcn_exp2f(x);
#else
    float r; asm("v_exp_f32 %0, %1" : "=v"(r) : "v"(x)); return r;
#endif
}
__device__ __forceinline__ float lane_pull(float v, int srclane) {  // pull v from lane srclane
    return __int_as_float(__builtin_amdgcn_ds_bpermute(srclane << 2, __float_as_int(v)));
}

// ---------------- merged prologue: cast x (blocks 0..2047), cast Wp (2048..2559),
// ---------------- transpose_w (2560..3327). Independent parts, one dispatch.
__global__ __launch_bounds__(256) void prologue(const float* __restrict__ x,
                                                const float* __restrict__ Wq,
                                                const float* __restrict__ Wk,
                                                const float* __restrict__ Wv,
                                                const float* __restrict__ Wp,
                                                ushort* __restrict__ xb,
                                                ushort* __restrict__ wpb,
                                                ushort* __restrict__ wt) {
    __shared__ __align__(16) ushort T[64 * 80];   // used by transpose_w part only
    const int bid = blockIdx.x;
    const int t = threadIdx.x;

    if (bid < 2048) {                      // cast x: 8M elements = 1M chunks of 8
        const int n8 = (int)((size_t)M_ * D_ / 8);
        int i = bid * 256 + t;
        const int stride = 2048 * 256;
        for (; i < n8; i += stride) {
            float4 a = ((const float4*)x)[2 * i];
            float4 b = ((const float4*)x)[2 * i + 1];
            short8 o;
            o[0] = (short)f2b(a.x); o[1] = (short)f2b(a.y);
            o[2] = (short)f2b(a.z); o[3] = (short)f2b(a.w);
            o[4] = (short)f2b(b.x); o[5] = (short)f2b(b.y);
            o[6] = (short)f2b(b.z); o[7] = (short)f2b(b.w);
            ((short8*)xb)[i] = o;
        }
    } else if (bid < 2560) {               // cast Wp: 1M elements = 128K chunks (512 blocks exactly)
        int i = (bid - 2048) * 256 + t;
        float4 a = ((const float4*)Wp)[2 * i];
        float4 b = ((const float4*)Wp)[2 * i + 1];
        short8 o;
        o[0] = (short)f2b(a.x); o[1] = (short)f2b(a.y);
        o[2] = (short)f2b(a.z); o[3] = (short)f2b(a.w);
        o[4] = (short)f2b(b.x); o[5] = (short)f2b(b.y);
        o[6] = (short)f2b(b.z); o[7] = (short)f2b(b.w);
        ((short8*)wpb)[i] = o;
    } else {                               // transpose_w: 768 blocks = 16 d-tiles x 48 heads
        const int q = bid - 2560;
        const int g = q >> 4;              // 0..47 (w*16+h)
        const int d0 = (q & 15) * 64;
        const float* W = (g < 16 ? Wq : (g < 32 ? Wk : Wv)) + (size_t)(g & 15) * (D_ * E_);
        #pragma unroll
        for (int it = 0; it < 4; ++it) {   // 64 d-rows x 16 float4 cols
            int i = it * 256 + t;
            int r = i >> 4, c = i & 15;
            float4 xx = *(const float4*)(W + (size_t)(d0 + r) * E_ + c * 4);
            T[(c * 4 + 0) * 80 + r] = f2b(xx.x);
            T[(c * 4 + 1) * 80 + r] = f2b(xx.y);
            T[(c * 4 + 2) * 80 + r] = f2b(xx.z);
            T[(c * 4 + 3) * 80 + r] = f2b(xx.w);
        }
        __syncthreads();
        #pragma unroll
        for (int it = 0; it < 2; ++it) {   // 64 e-rows x 8 chunks of 8
            int i = it * 256 + t;
            int e = i >> 3, c = i & 7;
            short8 xx = *(const short8*)&T[e * 80 + c * 8];
            *(short8*)&wt[((size_t)g * E_ + e) * D_ + d0 + c * 8] = xx;
        }
    }
}

// ---------------- QKV GEMM: [8192 x 1024] @ [1024 x 3072] (concat W), bf16 MFMA -------
// 2-phase double-buffered LDS: prefetch K-step k+1 BEFORE computing step k; one barrier
// per step. 48 KB LDS. w==2 (V) blocks write TRANSPOSED [bh][e][s] directly.
__global__ __launch_bounds__(512) void gemm_qkv(const ushort* __restrict__ xb,
                                                const ushort* __restrict__ wt,
                                                ushort* __restrict__ qk,
                                                ushort* __restrict__ vt) {
    const int m0 = blockIdx.x * 256;
    const int n0 = blockIdx.y * 128;
    const int w  = n0 >> 10;             // 0:q 1:k 2:v (block-uniform)

    __shared__ __align__(16) ushort As[2][256 * 32];   // swizzled, double-buffered
    __shared__ __align__(16) ushort Bs[2][128 * 32];

    const int t = threadIdx.x, l = t & 63, wid = t >> 6;
    const int wm = (wid & 3) * 64, wn = (wid >> 2) * 64;
    floatx4 acc[4][4] = {};

    // prologue: stage first K-step into buf 0
    {
        #pragma unroll
        for (int it = 0; it < 2; ++it) {
            int i = it * 512 + t;
            int r = i >> 2, cs = i & 3;
            int c = cs ^ ((r >> 1) & 3);
            GLD16(xb + (size_t)(m0 + r) * D_ + c * 8, &As[0][i * 8]);
        }
        int r = t >> 2, cs = t & 3;
        int c = cs ^ ((r >> 1) & 3);
        GLD16(wt + (size_t)(n0 + r) * D_ + c * 8, &Bs[0][t * 8]);
    }
    __syncthreads();

    int buf = 0;
    for (int k0 = 0; k0 < D_; k0 += 32) {
        // prefetch next K-step into buf^1 BEFORE compute
        if (k0 + 32 < D_) {
            #pragma unroll
            for (int it = 0; it < 2; ++it) {
                int i = it * 512 + t;
                int r = i >> 2, cs = i & 3;
                int c = cs ^ ((r >> 1) & 3);
                GLD16(xb + (size_t)(m0 + r) * D_ + k0 + 32 + c * 8, &As[buf ^ 1][i * 8]);
            }
            int r = t >> 2, cs = t & 3;
            int c = cs ^ ((r >> 1) & 3);
            GLD16(wt + (size_t)(n0 + r) * D_ + k0 + 32 + c * 8, &Bs[buf ^ 1][t * 8]);
        }

        short8 af[4], bf[4];
        #pragma unroll
        for (int mf = 0; mf < 4; ++mf) {
            int row = wm + 16 * mf + (l & 15);
            int c = (l >> 4) ^ ((row >> 1) & 3);
            af[mf] = *(const short8*)&As[buf][row * 32 + c * 8];
        }
        #pragma unroll
        for (int nf = 0; nf < 4; ++nf) {
            int row = wn + 16 * nf + (l & 15);
            int c = (l >> 4) ^ ((row >> 1) & 3);
            bf[nf] = *(const short8*)&Bs[buf][row * 32 + c * 8];
        }
        #pragma unroll
        for (int mf = 0; mf < 4; ++mf)
            #pragma unroll
            for (int nf = 0; nf < 4; ++nf)
                acc[mf][nf] = __builtin_amdgcn_mfma_f32_16x16x32_bf16(af[mf], bf[nf], acc[mf][nf], 0, 0, 0);

        __syncthreads();   // drains prefetch vmcnt + all waves done reading buf
        buf ^= 1;
    }

    if (w < 2) {
        ushort* outw = qk + (size_t)w * ((size_t)B_ * H_ * S_ * E_);
        #pragma unroll
        for (int mf = 0; mf < 4; ++mf)
            #pragma unroll
            for (int nf = 0; nf < 4; ++nf) {
                int n = n0 + wn + 16 * nf + (l & 15);
                int h = (n >> 6) & 15, e = n & 63;
                #pragma unroll
                for (int r = 0; r < 4; ++r) {
                    int m = m0 + wm + 16 * mf + (l >> 4) * 4 + r;
                    int b = m >> 11, s = m & (S_ - 1);
                    outw[((size_t)((b << 4) + h) * S_ + s) * E_ + e] = f2b(acc[mf][nf][r]);
                }
            }
    } else {
        #pragma unroll
        for (int mf = 0; mf < 4; ++mf) {
            int m = m0 + wm + 16 * mf + (l >> 4) * 4;
            int b = m >> 11, s = m & (S_ - 1);
            #pragma unroll
            for (int nf = 0; nf < 4; ++nf) {
                int n = n0 + wn + 16 * nf + (l & 15);
                int h = (n >> 6) & 15, e = n & 63;
                unsigned pk0 = cvt_pk_bf16(acc[mf][nf][0], acc[mf][nf][1]);
                unsigned pk1 = cvt_pk_bf16(acc[mf][nf][2], acc[mf][nf][3]);
                *(uint2*)&vt[((size_t)((b << 4) + h) * E_ + e) * S_ + s] = make_uint2(pk0, pk1);
            }
        }
    }
}

// ---------------- Flash attention (causal), bf16 MFMA, swapped QK^T ----------------
// ROUND-14 VERSION (measured 92 us, VGPR 72, 2 blocks/CU, LDS-pipe ~100% utilized).
// Accumulator-state growth falsified 3x (rounds 6, 17 M_rep=2; round 22 32x32 frags):
// +state -> VGPR > ~80 -> residency halves -> net regression. This is the optimum of
// the design family. grid: 1024 blocks; x = n>>6, bh = n&63 (XCD-aligned).
__global__ __launch_bounds__(256) void flash(const ushort* __restrict__ qg,
                                             const ushort* __restrict__ kg,
                                             const ushort* __restrict__ vtg,
                                             ushort* __restrict__ attn) {
    const int n = blockIdx.x;
    const int x = n >> 6;          // 0..15
    const int bh = n & 63;
    const int b = bh >> 4, h = bh & 15;
    const ushort* qb = qg + (size_t)bh * (S_ * E_);
    const ushort* kb = kg + (size_t)bh * (S_ * E_);
    const ushort* vb = vtg + (size_t)bh * (E_ * S_);

    __shared__ __align__(16) ushort QP[64 * 64];      // Q staging [q][e] swizzled, THEN per-wave P
    __shared__ __align__(16) ushort Ks[2][64 * 64];   // [t][e]   swizzled, double-buffered
    __shared__ __align__(16) ushort Vs[2][64 * 64];   // [e][j]   swizzled, double-buffered

    const int t = threadIdx.x, l = t & 63, wid = t >> 6;
    const float SC = 0.18033688f;                  // (1/sqrt(E)) * log2(e)
    const float NEG_INF = -__builtin_inff();
    const int g = l >> 4;                          // kv-lane-group 0..3
    const int qloc = l & 15;                       // this lane's q-row (wave-local)
    const int qts[2] = {x, 31 - x};
    ushort* Pw = &QP[wid * 1024];                  // this wave's 16x64 P quarter

    #pragma unroll 1
    for (int qi = 0; qi < 2; ++qi) {
        const int qt = qts[qi];

        // prologue: stage Q + first K/V tile
        #pragma unroll
        for (int it = 0; it < 2; ++it) {
            int i = it * 256 + t;
            int r = i >> 3, cs = i & 7, c = cs ^ (r & 7);
            GLD16(qb + (size_t)(qt * 64 + r) * E_ + c * 8, &QP[i * 8]);
            GLD16(kb + (size_t)r * E_ + c * 8, &Ks[0][i * 8]);
            GLD16(vb + (size_t)r * S_ + c * 8, &Vs[0][i * 8]);
        }
        __syncthreads();

        short8 qf[2];   // Q fragment lives in registers; QP is dead for Q after this
        #pragma unroll
        for (int ks = 0; ks < 2; ++ks) {
            int row = wid * 16 + qloc;
            int c = (g + 4 * ks) ^ (row & 7);
            qf[ks] = *(const short8*)&QP[row * 64 + c * 8];
        }

        floatx4 o[4] = {};
        float mr = NEG_INF, lr = 0.f;

        int buf = 0;
        for (int jt = 0; jt <= qt; ++jt) {
            // issue next tile's staging BEFORE compute (latency hides under compute)
            if (jt < qt) {
                #pragma unroll
                for (int it = 0; it < 2; ++it) {
                    int i = it * 256 + t;
                    int r = i >> 3, cs = i & 7, c = cs ^ (r & 7);
                    GLD16(kb + (size_t)((jt + 1) * 64 + r) * E_ + c * 8, &Ks[buf ^ 1][i * 8]);
                    GLD16(vb + (size_t)r * S_ + (jt + 1) * 64 + c * 8, &Vs[buf ^ 1][i * 8]);
                }
            }

            // S = Q K^T, SWAPPED operands: s[nf][r] = S[q = wid*16+qloc][kv = 16nf+4g+r]
            floatx4 s[4] = {};
            #pragma unroll
            for (int nf = 0; nf < 4; ++nf) {
                #pragma unroll
                for (int ks = 0; ks < 2; ++ks) {
                    int row = 16 * nf + qloc;
                    int c = (g + 4 * ks) ^ (row & 7);
                    short8 kf = *(const short8*)&Ks[buf][row * 64 + c * 8];
                    s[nf] = __builtin_amdgcn_mfma_f32_16x16x32_bf16(kf, qf[ks], s[nf], 0, 0, 0);
                }
            }

            // causal mask on diagonal tile only (raw scores, -inf); kv > q within tile
            if (jt == qt) {
                int qrow = wid * 16 + qloc;
                #pragma unroll
                for (int nf = 0; nf < 4; ++nf)
                    #pragma unroll
                    for (int r = 0; r < 4; ++r)
                        if (16 * nf + 4 * g + r > qrow) s[nf][r] = NEG_INF;
            }

            // row max: 15 in-lane fmax + 2 cross-lane (xor16, xor32); defer-max check
            float mx = s[0][0];
            #pragma unroll
            for (int nf = 0; nf < 4; ++nf)
                #pragma unroll
                for (int r = 0; r < 4; ++r) mx = fmaxf(mx, s[nf][r]);
            mx = fmaxf(mx, __shfl_xor(mx, 16));
            mx = fmaxf(mx, __shfl_xor(mx, 32));
            bool ok = (mx - mr) * SC <= 8.0f;

            if (!__all(ok)) {   // rescale path (rare after warm-up)
                float mn = fmaxf(mr, mx);
                float al = fast_exp2((mr - mn) * SC);
                mr = mn;
                lr *= al;
                #pragma unroll
                for (int r = 0; r < 4; ++r) {      // o rows are q-local 4g+r -> pull their alpha
                    float alq = lane_pull(al, 4 * g + r);
                    #pragma unroll
                    for (int nf = 0; nf < 4; ++nf) o[nf][r] *= alq;
                }
            }

            // exp2(fma) + lane-partial row sum (fully lane-local)
            {
                float nm = -mr * SC;
                float rs = 0.f;
                #pragma unroll
                for (int nf = 0; nf < 4; ++nf)
                    #pragma unroll
                    for (int r = 0; r < 4; ++r) {
                        float p = fast_exp2(fmaf(s[nf][r], SC, nm));
                        s[nf][r] = p;
                        rs += p;
                    }
                lr += rs;
            }

            // P -> wave-private quarter: 4 contiguous kv per nf -> ONE b64 write
            #pragma unroll
            for (int nf = 0; nf < 4; ++nf) {
                unsigned pk0 = cvt_pk_bf16(s[nf][0], s[nf][1]);
                unsigned pk1 = cvt_pk_bf16(s[nf][2], s[nf][3]);
                int chunk = 2 * nf + (g >> 1);
                int sw = chunk ^ (qloc & 7);
                int a = qloc * 64 + sw * 8 + 4 * (g & 1);
                *(uint2*)&Pw[a] = make_uint2(pk0, pk1);
            }

            // O += P V (A-frag read matches the written [q][kv] layout)
            short8 pf[2];
            #pragma unroll
            for (int ks = 0; ks < 2; ++ks) {
                int row = l & 15;
                int c = (g + 4 * ks) ^ (row & 7);
                pf[ks] = *(const short8*)&Pw[row * 64 + c * 8];
            }
            #pragma unroll
            for (int nf = 0; nf < 4; ++nf) {
                #pragma unroll
                for (int ks = 0; ks < 2; ++ks) {
                    int row = 16 * nf + (l & 15);
                    int c = (g + 4 * ks) ^ (row & 7);
                    short8 vf = *(const short8*)&Vs[buf][row * 64 + c * 8];
                    o[nf] = __builtin_amdgcn_mfma_f32_16x16x32_bf16(pf[ks], vf, o[nf], 0, 0, 0);
                }
            }

            __syncthreads();   // drains this iteration's prefetch (vmcnt) + protects buf^1
            buf ^= 1;
        }

        // epilogue: complete row sums (xor16+xor32), distribute 1/l to o-rows, write out
        lr += __shfl_xor(lr, 16);
        lr += __shfl_xor(lr, 32);
        float inv = 1.0f / lr;
        float il[4];
        #pragma unroll
        for (int r = 0; r < 4; ++r) il[r] = lane_pull(inv, 4 * g + r);

        #pragma unroll
        for (int nf = 0; nf < 4; ++nf) {
            int col = 16 * nf + qloc;
            #pragma unroll
            for (int rp = 0; rp < 2; ++rp) {
                unsigned pk = cvt_pk_bf16(o[nf][2 * rp] * il[2 * rp],
                                          o[nf][2 * rp + 1] * il[2 * rp + 1]);
                int row0 = g * 4 + 2 * rp;
                int a0 = row0 * 64 + (((col >> 3)) ^ (row0 & 7)) * 8 + (col & 7);
                int a1 = (row0 + 1) * 64 + (((col >> 3)) ^ ((row0 + 1) & 7)) * 8 + (col & 7);
                Pw[a0] = (ushort)pk;
                Pw[a1] = (ushort)(pk >> 16);
            }
        }
        #pragma unroll
        for (int it = 0; it < 2; ++it) {               // 16 rows x 8 chunks per wave
            int i = it * 64 + l;
            int row = i >> 3, cc = i & 7;
            int c = cc ^ (row & 7);
            short8 vv = *(const short8*)&Pw[row * 64 + c * 8];
            int s_abs = qt * 64 + wid * 16 + row;
            *(short8*)&attn[((size_t)(b * S_ + s_abs)) * D_ + h * E_ + cc * 8] = vv;
        }
        __syncthreads();   // all waves done with QP before next q-tile's Q staging
    }
}

// ---------------- output projection: [8192x1024] x Wp^T + bp, bf16 MFMA, fp32 out ----
// 2-phase double-buffered LDS. 32 KB LDS.
__global__ __launch_bounds__(256) void out_proj(const ushort* __restrict__ a,
                                                const ushort* __restrict__ wpb,
                                                const float* __restrict__ bp,
                                                float* __restrict__ out) {
    const int m0 = blockIdx.x * 128;
    const int n0 = blockIdx.y * 128;

    __shared__ __align__(16) ushort As[2][128 * 32];
    __shared__ __align__(16) ushort Bs[2][128 * 32];

    const int t = threadIdx.x, l = t & 63, wid = t >> 6;
    const int wm = (wid & 1) * 64, wn = (wid >> 1) * 64;
    floatx4 acc[4][4] = {};

    // prologue: stage first K-step into buf 0
    #pragma unroll
    for (int it = 0; it < 2; ++it) {
        int i = it * 256 + t;
        int r = i >> 2, cs = i & 3;
        int c = cs ^ ((r >> 1) & 3);
        GLD16(a + (size_t)(m0 + r) * D_ + c * 8, &As[0][i * 8]);
        GLD16(wpb + (size_t)(n0 + r) * D_ + c * 8, &Bs[0][i * 8]);
    }
    __syncthreads();

    int buf = 0;
    for (int k0 = 0; k0 < D_; k0 += 32) {
        if (k0 + 32 < D_) {
            #pragma unroll
            for (int it = 0; it < 2; ++it) {
                int i = it * 256 + t;
                int r = i >> 2, cs = i & 3;
                int c = cs ^ ((r >> 1) & 3);
                GLD16(a + (size_t)(m0 + r) * D_ + k0 + 32 + c * 8, &As[buf ^ 1][i * 8]);
                GLD16(wpb + (size_t)(n0 + r) * D_ + k0 + 32 + c * 8, &Bs[buf ^ 1][i * 8]);
            }
        }

        short8 af[4], bf[4];
        #pragma unroll
        for (int mf = 0; mf < 4; ++mf) {
            int row = wm + 16 * mf + (l & 15);
            int c = (l >> 4) ^ ((row >> 1) & 3);
            af[mf] = *(const short8*)&As[buf][row * 32 + c * 8];
        }
        #pragma unroll
        for (int nf = 0; nf < 4; ++nf) {
            int row = wn + 16 * nf + (l & 15);
            int c = (l >> 4) ^ ((row >> 1) & 3);
            bf[nf] = *(const short8*)&Bs[buf][row * 32 + c * 8];
        }
        #pragma unroll
        for (int mf = 0; mf < 4; ++mf)
            #pragma unroll
            for (int nf = 0; nf < 4; ++nf)
                acc[mf][nf] = __builtin_amdgcn_mfma_f32_16x16x32_bf16(af[mf], bf[nf], acc[mf][nf], 0, 0, 0);

        __syncthreads();   // drains prefetch vmcnt + all waves done reading buf
        buf ^= 1;
    }

    #pragma unroll
    for (int nf = 0; nf < 4; ++nf) {
        int col = n0 + wn + 16 * nf + (l & 15);
        float bias = bp[col];
        #pragma unroll
        for (int mf = 0; mf < 4; ++mf)
            #pragma unroll
            for (int r = 0; r < 4; ++r) {
                int m = m0 + wm + 16 * mf + (l >> 4) * 4 + r;
                out[(size_t)m * D_ + col] = acc[mf][nf][r] + bias;
            }
    }
}

extern "C" void kernel_launch(void* const* d_in, const int* in_sizes, int n_in,
                              void* d_out, int out_size, void* d_ws, size_t ws_size,
                              hipStream_t stream) {
    const float* x  = (const float*)d_in[0];
    const float* Wq = (const float*)d_in[1];
    const float* Wk = (const float*)d_in[2];
    const float* Wv = (const float*)d_in[3];
    const float* Wp = (const float*)d_in[4];
    const float* bp = (const float*)d_in[5];

    ushort* ws = (ushort*)d_ws;
    const size_t NX  = (size_t)M_ * D_;          // 8M
    const size_t NW  = (size_t)48 * E_ * D_;     // 3.15M
    const size_t NP  = (size_t)D_ * D_;          // 1M
    const size_t QSZ = (size_t)B_ * H_ * S_ * E_;// 8M
    ushort* xb    = ws;
    ushort* wt    = xb + NX;
    ushort* wpb   = wt + NW;
    ushort* qk    = wpb + NP;        // q | k
    ushort* vt    = qk + 2 * QSZ;    // v, transposed [bh][e][s]
    ushort* attnb = vt + QSZ;

    prologue <<<3328, 256, 0, stream>>>(x, Wq, Wk, Wv, Wp, xb, wpb, wt);
    gemm_qkv <<<dim3(M_ / 256, 24), 512, 0, stream>>>(xb, wt, qk, vt);
    flash    <<<1024, 256, 0, stream>>>(qk, qk + QSZ, vt, attnb);
    out_proj <<<dim3(M_ / 128, D_ / 128), 256, 0, stream>>>(attnb, wpb, bp, (float*)d_out);
}